// Round 1
// 287.951 us; speedup vs baseline: 1.0107x; 1.0107x over previous
//
#include <hip/hip_runtime.h>
#include <math.h>

#define Bn 64
#define In 2048
#define On 2048
#define Sn 10
#define Cn 512

#define OT 4            // o's per block
#define KT 64           // K tile
#define NP 48           // padded N: 40 dendrite + 4 synaptic + 4 zero
#define LROW 72         // padded row stride in bf16 elems (KT + 8)
#define NSTAGE (In / KT)

typedef short short8 __attribute__((ext_vector_type(8)));
typedef float f32x4 __attribute__((ext_vector_type(4)));

__device__ __forceinline__ unsigned short f2bf(float f) {
    union { float f; unsigned u; } v; v.f = f;
    unsigned r = (v.u + 0x7FFFu + ((v.u >> 16) & 1u)) >> 16;  // RNE
    return (unsigned short)r;
}

// blocks 0..63: ctx_signal[b] = mean(context[b,:]); blocks 64..575: x -> bf16
__global__ void prep_kernel(const float* __restrict__ x,
                            const float* __restrict__ ctx,
                            float* __restrict__ ws_ctx,
                            unsigned short* __restrict__ ws_xbf) {
    const int b = blockIdx.x;
    const int t = threadIdx.x;
    if (b < Bn) {
        __shared__ float red[256];
        float s = ctx[b * Cn + t] + ctx[b * Cn + t + 256];
        red[t] = s;
        __syncthreads();
        for (int off = 128; off > 0; off >>= 1) {
            if (t < off) red[t] += red[t + off];
            __syncthreads();
        }
        if (t == 0) ws_ctx[b] = red[0] * (1.0f / (float)Cn);
    } else {
        int idx = (b - Bn) * 256 + t;
        ws_xbf[idx] = f2bf(x[idx]);
    }
}

__global__ __launch_bounds__(256, 2)
void main_kernel(const unsigned short* __restrict__ xbf,
                 const float* __restrict__ wgt,
                 const float* __restrict__ cst,
                 const float* __restrict__ seg,
                 const float* __restrict__ bias,
                 const float* __restrict__ aact,
                 const float* __restrict__ athr,
                 const float* __restrict__ gates,
                 const float* __restrict__ prn,
                 const float* __restrict__ ws_ctx,
                 float* __restrict__ out) {
    __shared__ __align__(16) unsigned short Blds[2][NP * LROW];
    __shared__ float dsum[Bn][OT];
    __shared__ float ssum[Bn][OT];
    __shared__ float mastro[OT];

    const int t = threadIdx.x;
    const int o0 = blockIdx.x * OT;
    const int wave = t >> 6;
    const int lane = t & 63;
    const int l15 = lane & 15;
    const int q = lane >> 4;
    const float pthr = prn[0];

    // zero-init epilogue buffers (barriers in K-loop make this visible)
    ((float*)dsum)[t] = 0.0f;
    ((float*)ssum)[t] = 0.0f;

    // zero the pad rows 44..47 of both B buffers (never rewritten)
    for (int idx = t; idx < 4 * LROW; idx += 256) {
        Blds[0][44 * LROW + idx] = 0;
        Blds[1][44 * LROW + idx] = 0;
    }

    // mean_astro for this block's 4 outputs (threads 0..3)
    if (t < OT) {
        const int o = o0 + t;
        const float aa = aact[o], th = athr[o];
        float sum = 0.0f;
        for (int b2 = 0; b2 < Bn; ++b2) {
            float sg = 1.0f / (1.0f + expf(-ws_ctx[b2] * aa));
            if (sg > th) sum += sg;
        }
        mastro[t] = sum * (1.0f / (float)Bn);
    }

    // ---- coalesced seg staging: flat float2 index over the 4x(KT*Sn) chunk ----
    // per stage per block: 4 o-chunks x 2560 B contiguous = 1280 float2.
    // thread t handles f = t + 256*j, j = 0..4 (perfectly coalesced loads).
    const float* segp[5];
    int bofs[5];
#pragma unroll
    for (int j = 0; j < 5; ++j) {
        const int f = t + 256 * j;
        const int ol = f / 320;            // o_local 0..3
        const int rem = f - ol * 320;      // float2 within chunk
        const int io = rem / 5;            // i offset 0..63
        const int s2 = (rem - io * 5) * 2; // s in {0,2,4,6,8}; pair (s2, s2+1)
        segp[j] = seg + ((size_t)(o0 + ol) * In + io) * Sn + s2;
        bofs[j] = (ol * 10 + s2) * LROW + io;
    }
    // uniform w/cst staging: 1 float per thread per stage
    const float* wptr = wgt + (size_t)(o0 + wave) * In + lane;
    const float* cptr = cst + (size_t)(o0 + wave) * In + lane;
    const int wofs = (40 + wave) * LROW + lane;
    // A-fragments loaded straight from global (x tile is L1/L2-hot)
    const unsigned short* aptr = xbf + (size_t)(wave * 16 + l15) * In + q * 8;

    // two staging register sets (tile-parity cycled) + double-buffered A frags
    float2 svA[5], svB[5];
    float wvA, cvA, wvB, cvB;
    short8 aE0, aE1, aO0, aO1;

    f32x4 acc[3];
#pragma unroll
    for (int n = 0; n < 3; ++n) acc[n] = (f32x4){0.f, 0.f, 0.f, 0.f};

    auto loadB = [&](float2 (&sv)[5], float& wv, float& cv, int i0) {
        const int off = i0 * Sn;
#pragma unroll
        for (int j = 0; j < 5; ++j) sv[j] = *(const float2*)(segp[j] + off);
        wv = wptr[i0];
        cv = cptr[i0];
    };
    auto loadA = [&](short8& a0, short8& a1, int i0) {
        a0 = *(const short8*)(aptr + i0);
        a1 = *(const short8*)(aptr + i0 + 32);
    };
    auto storeB = [&](float2 (&sv)[5], float wv, float cv, int bb) {
        unsigned short* Bl = Blds[bb];
#pragma unroll
        for (int j = 0; j < 5; ++j) {
            Bl[bofs[j]] = f2bf(sv[j].x);
            Bl[bofs[j] + LROW] = f2bf(sv[j].y);
        }
        const float e = (__builtin_fabsf(wv) * cv > pthr) ? wv : 0.0f;
        Bl[wofs] = f2bf(e);
    };
    auto compute = [&](short8 a0, short8 a1, int bb) {
        const unsigned short* Bp = &Blds[bb][l15 * LROW + q * 8];
        short8 b0 = *(const short8*)(Bp);
        short8 b1 = *(const short8*)(Bp + 16 * LROW);
        short8 b2 = *(const short8*)(Bp + 32 * LROW);
        acc[0] = __builtin_amdgcn_mfma_f32_16x16x32_bf16(a0, b0, acc[0], 0, 0, 0);
        acc[1] = __builtin_amdgcn_mfma_f32_16x16x32_bf16(a0, b1, acc[1], 0, 0, 0);
        acc[2] = __builtin_amdgcn_mfma_f32_16x16x32_bf16(a0, b2, acc[2], 0, 0, 0);
        short8 c0 = *(const short8*)(Bp + 32);
        short8 c1 = *(const short8*)(Bp + 16 * LROW + 32);
        short8 c2 = *(const short8*)(Bp + 32 * LROW + 32);
        acc[0] = __builtin_amdgcn_mfma_f32_16x16x32_bf16(a1, c0, acc[0], 0, 0, 0);
        acc[1] = __builtin_amdgcn_mfma_f32_16x16x32_bf16(a1, c1, acc[1], 0, 0, 0);
        acc[2] = __builtin_amdgcn_mfma_f32_16x16x32_bf16(a1, c2, acc[2], 0, 0, 0);
    };

    // ---- 2-deep pipelined K loop (branch-free body; tail loads clamped) ----
    loadB(svA, wvA, cvA, 0);          // tile 0
    loadB(svB, wvB, cvB, KT);         // tile 1
    loadA(aE0, aE1, 0);               // A frags tile 0
    loadA(aO0, aO1, KT);              // A frags tile 1
    storeB(svA, wvA, cvA, 0);         // tile 0 -> lds0 (only latency exposed once)
    loadB(svA, wvA, cvA, 2 * KT);     // tile 2
    __syncthreads();

    const int ILAST = (NSTAGE - 1) * KT;
    for (int p = 0; p < NSTAGE / 2; ++p) {
        const int itE = 2 * p;
        const int itO = 2 * p + 1;
        const int iE2 = (itE + 2 < NSTAGE) ? (itE + 2) * KT : ILAST;  // A frags tile 2p+2
        const int iO2 = (itO + 2 < NSTAGE) ? (itO + 2) * KT : ILAST;  // A frags / segB tile 2p+3
        const int iA4 = (itE + 4 < NSTAGE) ? (itE + 4) * KT : ILAST;  // segA tile 2p+4
        // even iter: tile 2p in lds0
        compute(aE0, aE1, 0);
        loadA(aE0, aE1, iE2);
        storeB(svB, wvB, cvB, 1);     // tile 2p+1 (loads issued 2 iters ago)
        loadB(svB, wvB, cvB, iO2);    // tile 2p+3
        __syncthreads();
        // odd iter: tile 2p+1 in lds1
        compute(aO0, aO1, 1);
        loadA(aO0, aO1, iO2);
        storeB(svA, wvA, cvA, 0);     // tile 2p+2 (junk at p=15: lds0 never read again)
        loadB(svA, wvA, cvA, iA4);    // tile 2p+4
        __syncthreads();
    }

    // ---- epilogue ----
    // D[m][n]: m = wave*16 + q*4 + r, n = nt*16 + l15
    const int brow = wave * 16 + q * 4;
#pragma unroll
    for (int nt = 0; nt < 3; ++nt) {
        const int n = nt * 16 + l15;
        if (n < 40) {
            const int ol = n / 10;
            const int s = n - ol * 10;
            const float g = 1.0f / (1.0f + expf(-gates[(o0 + ol) * Sn + s]));
#pragma unroll
            for (int r = 0; r < 4; ++r) {
                float v = acc[nt][r];
                v = v > 0.0f ? v : 0.0f;
                atomicAdd(&dsum[brow + r][ol], v * g);
            }
        } else if (n < 44) {
            const int ol = n - 40;
#pragma unroll
            for (int r = 0; r < 4; ++r) ssum[brow + r][ol] = acc[nt][r];
        }
    }
    __syncthreads();
    {
        const int m = t >> 2;
        const int ol = t & 3;
        const int o = o0 + ol;
        float v = dsum[m][ol] + mastro[ol] * ssum[m][ol] + bias[o];
        out[(size_t)m * On + o] = v > 0.0f ? v : 0.0f;
    }
}

extern "C" void kernel_launch(void* const* d_in, const int* in_sizes, int n_in,
                              void* d_out, int out_size, void* d_ws, size_t ws_size,
                              hipStream_t stream) {
    (void)in_sizes; (void)n_in; (void)out_size; (void)ws_size;
    const float* x    = (const float*)d_in[0];
    const float* ctx  = (const float*)d_in[1];
    // d_in[2] prev_activation: unused by the reference
    const float* wgt  = (const float*)d_in[3];
    const float* bias = (const float*)d_in[4];
    const float* aact = (const float*)d_in[5];
    const float* athr = (const float*)d_in[6];
    const float* seg  = (const float*)d_in[7];
    const float* gat  = (const float*)d_in[8];
    const float* cst  = (const float*)d_in[9];
    const float* prn  = (const float*)d_in[10];
    float* out = (float*)d_out;

    float* ws_ctx = (float*)d_ws;
    unsigned short* ws_xbf = (unsigned short*)((char*)d_ws + 256);

    prep_kernel<<<Bn + (Bn * In) / 256, 256, 0, stream>>>(x, ctx, ws_ctx, ws_xbf);
    main_kernel<<<On / OT, 256, 0, stream>>>(ws_xbf, wgt, cst, seg, bias, aact,
                                             athr, gat, prn, ws_ctx, out);
}